// Round 2
// baseline (4771.125 us; speedup 1.0000x reference)
//
#include <hip/hip_runtime.h>
#include <hip/hip_bf16.h>

#define S_LEN 4096
#define E_DIM 512
#define B_DIM 2
#define M_ROWS (B_DIM * S_LEN)   // 8192

// C[m, n] = sum_k A[m,k] * W[n,k]   (A fp32 [M,512], W fp32 [512,512], C fp32)
// grid: (N/64, M/64, 3) ; z selects (Wq->Q, Wk->K, Wv->V)
__global__ __launch_bounds__(256) void qkv_gemm(
    const float* __restrict__ X,
    const float* __restrict__ Wq, const float* __restrict__ Wk, const float* __restrict__ Wv,
    float* __restrict__ Q, float* __restrict__ Kout, float* __restrict__ Vout)
{
    const int n0 = blockIdx.x * 64;
    const int m0 = blockIdx.y * 64;
    const int which = blockIdx.z;
    const float* __restrict__ W = (which == 0) ? Wq : (which == 1) ? Wk : Wv;
    float* __restrict__ C = (which == 0) ? Q : (which == 1) ? Kout : Vout;

    const int tid = threadIdx.x;
    const int ty = tid >> 4, tx = tid & 15;

    __shared__ float As[64][33];
    __shared__ float Bs[64][33];

    float acc[4][4];
#pragma unroll
    for (int i = 0; i < 4; ++i)
#pragma unroll
        for (int j = 0; j < 4; ++j) acc[i][j] = 0.f;

    const int lrow = tid >> 2;           // 0..63
    const int lc8  = (tid & 3) * 8;      // 0,8,16,24

    for (int k0 = 0; k0 < E_DIM; k0 += 32) {
        {
            const float* asrc = X + (size_t)(m0 + lrow) * E_DIM + k0 + lc8;
            float4 a0 = *(const float4*)(asrc);
            float4 a1 = *(const float4*)(asrc + 4);
            As[lrow][lc8 + 0] = a0.x; As[lrow][lc8 + 1] = a0.y;
            As[lrow][lc8 + 2] = a0.z; As[lrow][lc8 + 3] = a0.w;
            As[lrow][lc8 + 4] = a1.x; As[lrow][lc8 + 5] = a1.y;
            As[lrow][lc8 + 6] = a1.z; As[lrow][lc8 + 7] = a1.w;
            const float* bsrc = W + (size_t)(n0 + lrow) * E_DIM + k0 + lc8;
            float4 b0 = *(const float4*)(bsrc);
            float4 b1 = *(const float4*)(bsrc + 4);
            Bs[lrow][lc8 + 0] = b0.x; Bs[lrow][lc8 + 1] = b0.y;
            Bs[lrow][lc8 + 2] = b0.z; Bs[lrow][lc8 + 3] = b0.w;
            Bs[lrow][lc8 + 4] = b1.x; Bs[lrow][lc8 + 5] = b1.y;
            Bs[lrow][lc8 + 6] = b1.z; Bs[lrow][lc8 + 7] = b1.w;
        }
        __syncthreads();
#pragma unroll
        for (int k = 0; k < 32; ++k) {
            float a[4], b[4];
#pragma unroll
            for (int i = 0; i < 4; ++i) a[i] = As[ty * 4 + i][k];
#pragma unroll
            for (int j = 0; j < 4; ++j) b[j] = Bs[tx * 4 + j][k];
#pragma unroll
            for (int i = 0; i < 4; ++i)
#pragma unroll
                for (int j = 0; j < 4; ++j) acc[i][j] += a[i] * b[j];
        }
        __syncthreads();
    }

#pragma unroll
    for (int i = 0; i < 4; ++i)
#pragma unroll
        for (int j = 0; j < 4; ++j)
            C[(size_t)(m0 + ty * 4 + i) * E_DIM + n0 + tx * 4 + j] = acc[i][j];
}

// out[m, n] = sum_k AO[m,k] * Wo[n,k] + bo[n]   (all fp32)
__global__ __launch_bounds__(256) void out_gemm(
    const float* __restrict__ AO, const float* __restrict__ Wo,
    const float* __restrict__ bo, float* __restrict__ out)
{
    const int n0 = blockIdx.x * 64;
    const int m0 = blockIdx.y * 64;
    const int tid = threadIdx.x;
    const int ty = tid >> 4, tx = tid & 15;

    __shared__ float As[64][33];
    __shared__ float Bs[64][33];

    float acc[4][4];
#pragma unroll
    for (int i = 0; i < 4; ++i)
#pragma unroll
        for (int j = 0; j < 4; ++j) acc[i][j] = 0.f;

    const int lrow = tid >> 2;
    const int lc8  = (tid & 3) * 8;

    for (int k0 = 0; k0 < E_DIM; k0 += 32) {
        {
            const float* asrc = AO + (size_t)(m0 + lrow) * E_DIM + k0 + lc8;
            float4 a0 = *(const float4*)(asrc);
            float4 a1 = *(const float4*)(asrc + 4);
            As[lrow][lc8 + 0] = a0.x; As[lrow][lc8 + 1] = a0.y;
            As[lrow][lc8 + 2] = a0.z; As[lrow][lc8 + 3] = a0.w;
            As[lrow][lc8 + 4] = a1.x; As[lrow][lc8 + 5] = a1.y;
            As[lrow][lc8 + 6] = a1.z; As[lrow][lc8 + 7] = a1.w;
            const float* bsrc = Wo + (size_t)(n0 + lrow) * E_DIM + k0 + lc8;
            float4 b0 = *(const float4*)(bsrc);
            float4 b1 = *(const float4*)(bsrc + 4);
            Bs[lrow][lc8 + 0] = b0.x; Bs[lrow][lc8 + 1] = b0.y;
            Bs[lrow][lc8 + 2] = b0.z; Bs[lrow][lc8 + 3] = b0.w;
            Bs[lrow][lc8 + 4] = b1.x; Bs[lrow][lc8 + 5] = b1.y;
            Bs[lrow][lc8 + 6] = b1.z; Bs[lrow][lc8 + 7] = b1.w;
        }
        __syncthreads();
#pragma unroll
        for (int k = 0; k < 32; ++k) {
            float a[4], b[4];
#pragma unroll
            for (int i = 0; i < 4; ++i) a[i] = As[ty * 4 + i][k];
#pragma unroll
            for (int j = 0; j < 4; ++j) b[j] = Bs[tx * 4 + j][k];
#pragma unroll
            for (int i = 0; i < 4; ++i)
#pragma unroll
                for (int j = 0; j < 4; ++j) acc[i][j] += a[i] * b[j];
        }
        __syncthreads();
    }

#pragma unroll
    for (int i = 0; i < 4; ++i)
#pragma unroll
        for (int j = 0; j < 4; ++j) {
            float v = acc[i][j] + bo[n0 + tx * 4 + j];
            out[(size_t)(m0 + ty * 4 + i) * E_DIM + n0 + tx * 4 + j] = v;
        }
}

// Anti-causal flash attention: row i attends keys j >= i.
// grid: (S/32, B), 256 threads. Q-tile 32 rows, key tile 32.
__global__ __launch_bounds__(256) void flash_att(
    const float* __restrict__ Q, const float* __restrict__ K,
    const float* __restrict__ V, float* __restrict__ O)
{
    const int b  = blockIdx.y;
    const int i0 = blockIdx.x * 32;
    const int tid = threadIdx.x;
    const int ty = tid >> 4, tx = tid & 15;
    const float scale = 0.044194173824159216f; // 1/sqrt(512)

    __shared__ float Qc[32][33];
    __shared__ float Kc[32][33];
    __shared__ float Ps[32][33];
    __shared__ float Vs[32][68];
    __shared__ float mrow[32], lsum[32], arow[32];

    float o[2][8][4];
#pragma unroll
    for (int i = 0; i < 2; ++i)
#pragma unroll
        for (int c = 0; c < 8; ++c)
#pragma unroll
            for (int q = 0; q < 4; ++q) o[i][c][q] = 0.f;

    if (tid < 32) { mrow[tid] = -__builtin_inff(); lsum[tid] = 0.f; }
    __syncthreads();

    const float* Qb = Q + (size_t)b * S_LEN * E_DIM;
    const float* Kb = K + (size_t)b * S_LEN * E_DIM;
    const float* Vb = V + (size_t)b * S_LEN * E_DIM;
    float*       Ob = O + (size_t)b * S_LEN * E_DIM;

    const int ldr = tid >> 3;            // 0..31
    const int ldc = (tid & 7) * 4;       // 0..28
    const int vlc = (tid & 7) * 8;       // 0..56

    for (int j0 = i0; j0 < S_LEN; j0 += 32) {
        // ---- S tile: s[2][2] = Q[i0+2ty+{0,1}, :] . K[j0+2tx+{0,1}, :]
        float s[2][2] = {{0.f, 0.f}, {0.f, 0.f}};
        for (int e0 = 0; e0 < E_DIM; e0 += 32) {
            float4 q4 = *(const float4*)(Qb + (size_t)(i0 + ldr) * E_DIM + e0 + ldc);
            Qc[ldr][ldc + 0] = q4.x; Qc[ldr][ldc + 1] = q4.y;
            Qc[ldr][ldc + 2] = q4.z; Qc[ldr][ldc + 3] = q4.w;
            float4 k4 = *(const float4*)(Kb + (size_t)(j0 + ldr) * E_DIM + e0 + ldc);
            Kc[ldr][ldc + 0] = k4.x; Kc[ldr][ldc + 1] = k4.y;
            Kc[ldr][ldc + 2] = k4.z; Kc[ldr][ldc + 3] = k4.w;
            __syncthreads();
#pragma unroll
            for (int e = 0; e < 32; ++e) {
                float q0 = Qc[2 * ty][e],     q1 = Qc[2 * ty + 1][e];
                float k0 = Kc[2 * tx][e],     k1 = Kc[2 * tx + 1][e];
                s[0][0] += q0 * k0; s[0][1] += q0 * k1;
                s[1][0] += q1 * k0; s[1][1] += q1 * k1;
            }
            __syncthreads();
        }
        // ---- scale + anti-causal mask (keep j >= i)
#pragma unroll
        for (int i = 0; i < 2; ++i)
#pragma unroll
            for (int j = 0; j < 2; ++j) {
                int gi = i0 + 2 * ty + i, gj = j0 + 2 * tx + j;
                Ps[2 * ty + i][2 * tx + j] =
                    (gj >= gi) ? s[i][j] * scale : -__builtin_inff();
            }
        __syncthreads();
        // ---- per-row online softmax stats
        if (tid < 32) {
            int r = tid;
            float mx = -__builtin_inff();
#pragma unroll
            for (int j = 0; j < 32; ++j) mx = fmaxf(mx, Ps[r][j]);
            float mold = mrow[r];
            float mnew = fmaxf(mold, mx);
            float al = __expf(mold - mnew);   // exp(-inf)=0 on first tile
            float sum = 0.f;
#pragma unroll
            for (int j = 0; j < 32; ++j) {
                float p = __expf(Ps[r][j] - mnew);
                Ps[r][j] = p;
                sum += p;
            }
            lsum[r] = lsum[r] * al + sum;
            mrow[r] = mnew;
            arow[r] = al;
        }
        __syncthreads();
        // ---- rescale accumulator
        float a0 = arow[2 * ty], a1 = arow[2 * ty + 1];
#pragma unroll
        for (int c = 0; c < 8; ++c)
#pragma unroll
            for (int q = 0; q < 4; ++q) { o[0][c][q] *= a0; o[1][c][q] *= a1; }
        // ---- P @ V, e in chunks of 64
#pragma unroll 1
        for (int c = 0; c < 8; ++c) {
            const int e0 = c * 64;
            const float* vsrc = Vb + (size_t)(j0 + ldr) * E_DIM + e0 + vlc;
            float4 v0 = *(const float4*)(vsrc);
            float4 v1 = *(const float4*)(vsrc + 4);
            *(float4*)&Vs[ldr][vlc]     = v0;
            *(float4*)&Vs[ldr][vlc + 4] = v1;
            __syncthreads();
#pragma unroll
            for (int jj = 0; jj < 32; ++jj) {
                float p0 = Ps[2 * ty][jj], p1 = Ps[2 * ty + 1][jj];
#pragma unroll
                for (int q = 0; q < 4; ++q) {
                    float v = Vs[jj][tx * 4 + q];
                    o[0][c][q] += p0 * v;
                    o[1][c][q] += p1 * v;
                }
            }
            __syncthreads();
        }
    }
    // ---- normalize + store
    float inv0 = 1.f / lsum[2 * ty], inv1 = 1.f / lsum[2 * ty + 1];
#pragma unroll
    for (int c = 0; c < 8; ++c)
#pragma unroll
        for (int q = 0; q < 4; ++q) {
            int col = c * 64 + tx * 4 + q;
            Ob[(size_t)(i0 + 2 * ty) * E_DIM + col]     = o[0][c][q] * inv0;
            Ob[(size_t)(i0 + 2 * ty + 1) * E_DIM + col] = o[1][c][q] * inv1;
        }
}

extern "C" void kernel_launch(void* const* d_in, const int* in_sizes, int n_in,
                              void* d_out, int out_size, void* d_ws, size_t ws_size,
                              hipStream_t stream) {
    (void)in_sizes; (void)n_in; (void)out_size; (void)ws_size;
    const float* x  = (const float*)d_in[0];
    const float* Wq = (const float*)d_in[1];
    const float* Wk = (const float*)d_in[2];
    const float* Wv = (const float*)d_in[3];
    const float* Wo = (const float*)d_in[4];
    const float* bo = (const float*)d_in[5];
    float* out = (float*)d_out;

    const size_t tsz = (size_t)M_ROWS * E_DIM; // 4,194,304 floats
    float* Q  = (float*)d_ws;
    float* K  = Q + tsz;
    float* V  = K + tsz;
    float* AO = V + tsz;

    dim3 gproj(E_DIM / 64, M_ROWS / 64, 3);
    qkv_gemm<<<gproj, 256, 0, stream>>>(x, Wq, Wk, Wv, Q, K, V);

    dim3 gatt(S_LEN / 32, B_DIM);
    flash_att<<<gatt, 256, 0, stream>>>(Q, K, V, AO);

    dim3 gout(E_DIM / 64, M_ROWS / 64);
    out_gemm<<<gout, 256, 0, stream>>>(AO, Wo, bo, out);
}

// Round 3
// 512.720 us; speedup vs baseline: 9.3055x; 9.3055x over previous
//
#include <hip/hip_runtime.h>
#include <hip/hip_bf16.h>

#define S_LEN 4096
#define E_DIM 512
#define B_DIM 2
#define M_ROWS (B_DIM * S_LEN)   // 8192

typedef __attribute__((ext_vector_type(8))) short short8;   // 8 bf16 = 4 VGPRs
typedef __attribute__((ext_vector_type(4))) float floatx4;  // MFMA C/D

__device__ __forceinline__ unsigned short f2bf(float f) {
    unsigned u = __float_as_uint(f);
    unsigned r = (u + 0x7fffu + ((u >> 16) & 1u)) >> 16;   // RNE
    return (unsigned short)r;
}

// ---------------- convert fp32 inputs -> bf16 workspace ----------------
// dst layout (contiguous): xb[4194304] Wq[262144] Wk[262144] Wv[262144] Wo[262144]
__global__ __launch_bounds__(256) void convert_bf16(
    const float* __restrict__ x,  const float* __restrict__ wq,
    const float* __restrict__ wk, const float* __restrict__ wv,
    const float* __restrict__ wo, unsigned short* __restrict__ dst)
{
    long i = (long)blockIdx.x * 1024 + (long)threadIdx.x * 4;
    const float* src; long off;
    if      (i < 4194304) { src = x;  off = i; }
    else if (i < 4456448) { src = wq; off = i - 4194304; }
    else if (i < 4718592) { src = wk; off = i - 4456448; }
    else if (i < 4980736) { src = wv; off = i - 4718592; }
    else                  { src = wo; off = i - 4980736; }
    float4 v = *(const float4*)(src + off);
    ushort4 o;
    o.x = f2bf(v.x); o.y = f2bf(v.y); o.z = f2bf(v.z); o.w = f2bf(v.w);
    *(ushort4*)(dst + i) = o;
}

// ---------------- MFMA GEMM core: C[m,n] = sum_k A[m,k]*W[n,k] ----------------
// A [M,512] bf16 row-major, W [512,512] bf16 row-major (row = out-feature).
// 128x128 tile, BK=32, 256 thr = 4 waves (2x2 of 64x64).
// mode 0: bf16 row-major; mode 1: bf16 V-transposed Vt[b][e][s]; mode 2: f32 + bias
__device__ __forceinline__ void gemm_core(
    const unsigned short* __restrict__ A, const unsigned short* __restrict__ W,
    void* __restrict__ Cv, const float* __restrict__ bias, int mode,
    int m0, int n0)
{
    __shared__ unsigned short As[128][40];   // +8 pad: frag ds_read_b128 2-way (free)
    __shared__ unsigned short Bs[128][40];
    const int tid = threadIdx.x;
    const int lane = tid & 63, wave = tid >> 6;
    const int wm = wave >> 1, wn = wave & 1;
    const int q4 = lane >> 4, l16 = lane & 15;

    floatx4 acc[4][4];
#pragma unroll
    for (int i = 0; i < 4; ++i)
#pragma unroll
        for (int j = 0; j < 4; ++j) acc[i][j] = (floatx4){0.f, 0.f, 0.f, 0.f};

    const int srow = tid >> 1;          // 0..127
    const int scol = (tid & 1) * 16;    // 0 or 16 (bf16 units)

    for (int k0 = 0; k0 < 512; k0 += 32) {
        {
            const unsigned short* pa = A + (size_t)(m0 + srow) * 512 + k0 + scol;
            uint4 a0 = *(const uint4*)pa;
            uint4 a1 = *(const uint4*)(pa + 8);
            *(uint4*)&As[srow][scol]     = a0;
            *(uint4*)&As[srow][scol + 8] = a1;
            const unsigned short* pb = W + (size_t)(n0 + srow) * 512 + k0 + scol;
            uint4 b0 = *(const uint4*)pb;
            uint4 b1 = *(const uint4*)(pb + 8);
            *(uint4*)&Bs[srow][scol]     = b0;
            *(uint4*)&Bs[srow][scol + 8] = b1;
        }
        __syncthreads();
        short8 af[4], bfr[4];
#pragma unroll
        for (int i = 0; i < 4; ++i) {
            af[i]  = *(const short8*)&As[wm * 64 + i * 16 + l16][q4 * 8];
            bfr[i] = *(const short8*)&Bs[wn * 64 + i * 16 + l16][q4 * 8];
        }
#pragma unroll
        for (int i = 0; i < 4; ++i)
#pragma unroll
            for (int j = 0; j < 4; ++j)
                acc[i][j] = __builtin_amdgcn_mfma_f32_16x16x32_bf16(af[i], bfr[j], acc[i][j], 0, 0, 0);
        __syncthreads();
    }

    // C/D layout: col = lane&15, row = (lane>>4)*4 + reg  [m89-verified]
    if (mode == 0) {
        unsigned short* C = (unsigned short*)Cv;
#pragma unroll
        for (int i = 0; i < 4; ++i) {
            int rowb = m0 + wm * 64 + i * 16 + q4 * 4;
#pragma unroll
            for (int j = 0; j < 4; ++j) {
                int col = n0 + wn * 64 + j * 16 + l16;
#pragma unroll
                for (int rg = 0; rg < 4; ++rg)
                    C[(size_t)(rowb + rg) * 512 + col] = f2bf(acc[i][j][rg]);
            }
        }
    } else if (mode == 1) {
        // Vt[b][e][s]; rows 4-aligned so never straddle the batch boundary (4096)
        unsigned short* C = (unsigned short*)Cv;
#pragma unroll
        for (int i = 0; i < 4; ++i) {
            int grow = m0 + wm * 64 + i * 16 + q4 * 4;
            int b = grow >> 12, s = grow & 4095;
#pragma unroll
            for (int j = 0; j < 4; ++j) {
                int e = n0 + wn * 64 + j * 16 + l16;
                ushort4 pk;
                pk.x = f2bf(acc[i][j][0]); pk.y = f2bf(acc[i][j][1]);
                pk.z = f2bf(acc[i][j][2]); pk.w = f2bf(acc[i][j][3]);
                *(ushort4*)(C + (size_t)b * 512 * 4096 + (size_t)e * 4096 + s) = pk;
            }
        }
    } else {
        float* C = (float*)Cv;
#pragma unroll
        for (int i = 0; i < 4; ++i) {
            int rowb = m0 + wm * 64 + i * 16 + q4 * 4;
#pragma unroll
            for (int j = 0; j < 4; ++j) {
                int col = n0 + wn * 64 + j * 16 + l16;
                float bv = bias[col];
#pragma unroll
                for (int rg = 0; rg < 4; ++rg)
                    C[(size_t)(rowb + rg) * 512 + col] = acc[i][j][rg] + bv;
            }
        }
    }
}

// grid (4, 64, 3): z=0 Q, z=1 K, z=2 V(transposed)
__global__ __launch_bounds__(256) void gemm_qkv(
    const unsigned short* __restrict__ xb,
    const unsigned short* __restrict__ Wqb, const unsigned short* __restrict__ Wkb,
    const unsigned short* __restrict__ Wvb,
    unsigned short* __restrict__ Qb, unsigned short* __restrict__ Kb,
    unsigned short* __restrict__ Vtb)
{
    const int z = blockIdx.z;
    const unsigned short* W = (z == 0) ? Wqb : (z == 1) ? Wkb : Wvb;
    unsigned short* C = (z == 0) ? Qb : (z == 1) ? Kb : Vtb;
    gemm_core(xb, W, C, nullptr, (z == 2) ? 1 : 0, blockIdx.y * 128, blockIdx.x * 128);
}

// grid (4, 64): AO @ Wo^T + bias -> fp32
__global__ __launch_bounds__(256) void gemm_out(
    const unsigned short* __restrict__ AOb, const unsigned short* __restrict__ Wob,
    const float* __restrict__ bo, float* __restrict__ out)
{
    gemm_core(AOb, Wob, out, bo, 2, blockIdx.y * 128, blockIdx.x * 128);
}

// ---------------- MFMA flash attention (anti-causal: keep j >= i) ----------------
// One 16-row Q tile per block; Tn=64 keys/step; 4 waves: QK split-K (128 each),
// PV split-N (128 cols each). Grid (256,2), tile swizzled for per-CU balance.
#define NEG_INF (-3.0e38f)
__global__ __launch_bounds__(256) void flash_mfma(
    const unsigned short* __restrict__ Qg, const unsigned short* __restrict__ Kg,
    const unsigned short* __restrict__ Vt, unsigned short* __restrict__ AO)
{
    const int bb = blockIdx.y;
    const int tile = (bb == 0) ? blockIdx.x : (255 - blockIdx.x);  // pair heavy+light per CU
    const int i0 = tile * 16;
    const int tid = threadIdx.x;
    const int lane = tid & 63, w = tid >> 6;
    const int q4 = lane >> 4, l16 = lane & 15;
    const float scale = 0.044194173824159216f;  // 1/sqrt(512)

    __shared__ float Sred[4][16][68];       // per-wave QK partials (stride 68: bank-uniform)
    __shared__ unsigned short Plds[16][72]; // P bf16, +8 pad (A-frag reads bank-uniform)
    __shared__ float arow[16], lrow[16];

    const size_t rowbase = (size_t)bb * S_LEN;

    // Q A-frags for this wave's K-slice [128w, 128w+128) — loaded once per tile
    short8 aq[4];
#pragma unroll
    for (int ks = 0; ks < 4; ++ks)
        aq[ks] = *(const short8*)(Qg + (rowbase + i0 + l16) * 512 + w * 128 + ks * 32 + q4 * 8);

    floatx4 oacc[8];
#pragma unroll
    for (int i = 0; i < 8; ++i) oacc[i] = (floatx4){0.f, 0.f, 0.f, 0.f};

    float m_old = NEG_INF, l_old = 0.f;
    const int r  = tid >> 4;   // softmax row 0..15 (wave w owns rows 4w..4w+3)
    const int sc = tid & 15;   // col group (4 cols)

    for (int j0 = i0 & ~63; j0 < S_LEN; j0 += 64) {
        // ---- QK^T partial (this wave's 128-wide K slice)
        floatx4 sfrag[4];
#pragma unroll
        for (int nf = 0; nf < 4; ++nf) sfrag[nf] = (floatx4){0.f, 0.f, 0.f, 0.f};
#pragma unroll
        for (int nf = 0; nf < 4; ++nf)
#pragma unroll
            for (int ks = 0; ks < 4; ++ks) {
                short8 bk = *(const short8*)(Kg + (rowbase + j0 + nf * 16 + l16) * 512 + w * 128 + ks * 32 + q4 * 8);
                sfrag[nf] = __builtin_amdgcn_mfma_f32_16x16x32_bf16(aq[ks], bk, sfrag[nf], 0, 0, 0);
            }
#pragma unroll
        for (int nf = 0; nf < 4; ++nf)
#pragma unroll
            for (int rg = 0; rg < 4; ++rg)
                Sred[w][q4 * 4 + rg][nf * 16 + l16] = sfrag[nf][rg];
        __syncthreads();

        // ---- cross-wave reduce + online softmax (thread: row r, cols 4sc..4sc+3)
        float4 s0 = *(const float4*)&Sred[0][r][4 * sc];
        float4 s1 = *(const float4*)&Sred[1][r][4 * sc];
        float4 s2 = *(const float4*)&Sred[2][r][4 * sc];
        float4 s3 = *(const float4*)&Sred[3][r][4 * sc];
        float sv[4] = { s0.x + s1.x + s2.x + s3.x, s0.y + s1.y + s2.y + s3.y,
                        s0.z + s1.z + s2.z + s3.z, s0.w + s1.w + s2.w + s3.w };
        float mx = NEG_INF;
#pragma unroll
        for (int j = 0; j < 4; ++j) {
            int cg = j0 + 4 * sc + j;
            sv[j] = (cg >= i0 + r) ? sv[j] * scale : NEG_INF;   // anti-causal mask
            mx = fmaxf(mx, sv[j]);
        }
#pragma unroll
        for (int off = 1; off < 16; off <<= 1)
            mx = fmaxf(mx, __shfl_xor(mx, off));
        float mnew  = fmaxf(m_old, mx);
        float alpha = __expf(m_old - mnew);
        float ps = 0.f;
        ushort4 pk;
        {
            float p0 = __expf(sv[0] - mnew), p1 = __expf(sv[1] - mnew);
            float p2 = __expf(sv[2] - mnew), p3 = __expf(sv[3] - mnew);
            ps = p0 + p1 + p2 + p3;
            pk.x = f2bf(p0); pk.y = f2bf(p1); pk.z = f2bf(p2); pk.w = f2bf(p3);
        }
        *(ushort4*)&Plds[r][4 * sc] = pk;
#pragma unroll
        for (int off = 1; off < 16; off <<= 1)
            ps += __shfl_xor(ps, off);
        l_old = l_old * alpha + ps;
        m_old = mnew;
        if (sc == 0) arow[r] = alpha;
        __syncthreads();

        // ---- rescale O, then PV (this wave owns output cols [128w, 128w+128))
        float al[4];
#pragma unroll
        for (int rg = 0; rg < 4; ++rg) al[rg] = arow[q4 * 4 + rg];
#pragma unroll
        for (int nf = 0; nf < 8; ++nf) {
            oacc[nf][0] *= al[0]; oacc[nf][1] *= al[1];
            oacc[nf][2] *= al[2]; oacc[nf][3] *= al[3];
        }
#pragma unroll
        for (int ks = 0; ks < 2; ++ks) {
            short8 ap = *(const short8*)&Plds[l16][ks * 32 + q4 * 8];
#pragma unroll
            for (int nf = 0; nf < 8; ++nf) {
                short8 bv = *(const short8*)(Vt + (size_t)bb * 512 * 4096
                              + (size_t)(w * 128 + nf * 16 + l16) * 4096 + j0 + ks * 32 + q4 * 8);
                oacc[nf] = __builtin_amdgcn_mfma_f32_16x16x32_bf16(ap, bv, oacc[nf], 0, 0, 0);
            }
        }
        __syncthreads();
    }

    if (sc == 0) lrow[r] = l_old;
    __syncthreads();
    float li[4];
#pragma unroll
    for (int rg = 0; rg < 4; ++rg) li[rg] = 1.f / lrow[q4 * 4 + rg];
#pragma unroll
    for (int nf = 0; nf < 8; ++nf) {
        int col = w * 128 + nf * 16 + l16;
#pragma unroll
        for (int rg = 0; rg < 4; ++rg)
            AO[(rowbase + i0 + q4 * 4 + rg) * 512 + col] = f2bf(oacc[nf][rg] * li[rg]);
    }
}

extern "C" void kernel_launch(void* const* d_in, const int* in_sizes, int n_in,
                              void* d_out, int out_size, void* d_ws, size_t ws_size,
                              hipStream_t stream) {
    (void)in_sizes; (void)n_in; (void)out_size; (void)ws_size;
    const float* x  = (const float*)d_in[0];
    const float* Wq = (const float*)d_in[1];
    const float* Wk = (const float*)d_in[2];
    const float* Wv = (const float*)d_in[3];
    const float* Wo = (const float*)d_in[4];
    const float* bo = (const float*)d_in[5];
    float* out = (float*)d_out;

    unsigned short* xb  = (unsigned short*)d_ws;   // 4194304
    unsigned short* Wqb = xb  + 4194304;           // 262144 each
    unsigned short* Wkb = Wqb + 262144;
    unsigned short* Wvb = Wkb + 262144;
    unsigned short* Wob = Wvb + 262144;
    unsigned short* Qb  = Wob + 262144;            // 4194304 each
    unsigned short* Kb  = Qb  + 4194304;
    unsigned short* Vtb = Kb  + 4194304;
    unsigned short* AOb = Vtb + 4194304;

    convert_bf16<<<5120, 256, 0, stream>>>(x, Wq, Wk, Wv, Wo, xb);

    gemm_qkv<<<dim3(4, 64, 3), 256, 0, stream>>>(xb, Wqb, Wkb, Wvb, Qb, Kb, Vtb);

    flash_mfma<<<dim3(256, 2), 256, 0, stream>>>(Qb, Kb, Vtb, AOb);

    gemm_out<<<dim3(4, 64), 256, 0, stream>>>(AOb, Wob, bo, out);
}